// Round 22
// baseline (132.710 us; speedup 1.0000x reference)
//
#include <hip/hip_runtime.h>
#include <cstdint>
#include <cstddef>

// ---------------------------------------------------------------------------
// mask_moe: bit-exact vs harness reference (verified r4-r21, absmax 0.0).
// FROZEN arithmetic: partitionable threefry bits, f32 sequential-k FMA dots,
// f32 elementwise chain (softplus/normal/softmax), decision logic.
// Round 22: revert loss path to r17 (r21 atomics regressed). Gating staging
// via __builtin_amdgcn_global_load_lds width=16 (no VGPR round-trip, no
// mid-loop vmcnt drain): linear [256][32] LDS tiles + both-sides XOR swizzle
// (pre-swizzled global source col (ln&7)^(ln>>3); read slot j^(t&7)) --
// bank-conflict level equals r17's pad-36; bufL[j] still gets ascending-k
// columns => FROZEN FMA order bit-identical. Out/loss: r17 byte-identical.
// ---------------------------------------------------------------------------

namespace {

constexpr int kBH = 256;                  // B*H
constexpr int kL = 512;                   // L
constexpr int kE = 3;                     // experts
constexpr int kRows = kBH * kL;           // 131072 gating rows

typedef float v4f __attribute__((ext_vector_type(4)));

// async global->LDS, 16B per lane; lds base wave-uniform, dest = base+lane*16
#define GLOAD_LDS16(GP, LP)                                                 \
  __builtin_amdgcn_global_load_lds(                                         \
      (const __attribute__((address_space(1))) uint32_t*)(GP),              \
      (__attribute__((address_space(3))) uint32_t*)(LP), 16, 0, 0)

__device__ __forceinline__ uint32_t rotl32(uint32_t v, int n) {
  return (v << n) | (v >> (32 - n));
}

// Threefry-2x32, 20 rounds, key = (0, 42)  [jax.random.key(42)]
__device__ __forceinline__ void threefry2x32_k42(uint32_t& x0, uint32_t& x1) {
  const uint32_t ks0 = 0u;
  const uint32_t ks1 = 42u;
  const uint32_t ks2 = 0u ^ 42u ^ 0x1BD11BDAu;
  x0 += ks0; x1 += ks1;
#define TF_ROUND(r) { x0 += x1; x1 = rotl32(x1, (r)); x1 ^= x0; }
  TF_ROUND(13) TF_ROUND(15) TF_ROUND(26) TF_ROUND(6)
  x0 += ks1; x1 += ks2 + 1u;
  TF_ROUND(17) TF_ROUND(29) TF_ROUND(16) TF_ROUND(24)
  x0 += ks2; x1 += ks0 + 2u;
  TF_ROUND(13) TF_ROUND(15) TF_ROUND(26) TF_ROUND(6)
  x0 += ks0; x1 += ks1 + 3u;
  TF_ROUND(17) TF_ROUND(29) TF_ROUND(16) TF_ROUND(24)
  x0 += ks1; x1 += ks2 + 4u;
  TF_ROUND(13) TF_ROUND(15) TF_ROUND(26) TF_ROUND(6)
  x0 += ks2; x1 += ks0 + 5u;
#undef TF_ROUND
}

// partitionable path: bits = x0 ^ x1 of threefry(key, (0, i))
__device__ __forceinline__ uint32_t jax_random_bits(uint32_t flat_idx) {
  uint32_t x0 = 0u;
  uint32_t x1 = flat_idx;
  threefry2x32_k42(x0, x1);
  return x0 ^ x1;
}

// jax.random.normal f32: uniform(-0.99999994, 1.0) then sqrt(2)*erfinv (XLA Giles poly)
__device__ float bits_to_normal(uint32_t bits) {
#pragma clang fp contract(off)
  const uint32_t fb = (bits >> 9) | 0x3F800000u;
  const float f = __uint_as_float(fb) - 1.0f;   // [0, 1)
  const float lo = -0.99999994f;                 // nextafterf(-1, 0)
  float u = f * 2.0f + lo;                       // (maxval-minval) == 2.0f exactly
  u = fmaxf(lo, u);
  float w = -log1pf(-(u * u));
  float p;
  if (w < 5.0f) {
    w = w - 2.5f;
    p = 2.81022636e-08f;
    p = 3.43273939e-07f + p * w;
    p = -3.5233877e-06f + p * w;
    p = -4.39150654e-06f + p * w;
    p = 0.00021858087f + p * w;
    p = -0.00125372503f + p * w;
    p = -0.00417768164f + p * w;
    p = 0.246640727f + p * w;
    p = 1.50140941f + p * w;
  } else {
    w = sqrtf(w) - 3.0f;
    p = -0.000200214257f;
    p = 0.000100950558f + p * w;
    p = 0.00134934322f + p * w;
    p = -0.00367342844f + p * w;
    p = 0.00573950773f + p * w;
    p = -0.0076224613f + p * w;
    p = 0.00943887047f + p * w;
    p = 1.00167406f + p * w;
    p = 2.83297682f + p * w;
  }
  const float einv = p * u;
  return 1.41421354f * einv;  // f32(sqrt(2)) * erfinv(u)
}

// jax.nn.softplus(x) = logaddexp(x, 0) = max(x,0) + log1p(exp(-|x|))
__device__ __forceinline__ float softplus_f32(float v) {
#pragma clang fp contract(off)
  const float amax = fmaxf(v, 0.0f);
  return amax + log1pf(expf(-fabsf(v)));
}

// 16 k-steps of the FROZEN ascending-k FMA sequence; weights via uniform
// global loads (gw/nw are const __restrict__).
#define COMP16(BUF, KB)                                                     \
  {                                                                         \
    _Pragma("unroll")                                                       \
    for (int j_ = 0; j_ < 4; ++j_) {                                        \
      const int k_ = (KB) + j_ * 4;                                         \
      const float4 wg0 = *reinterpret_cast<const float4*>(gw + k_);         \
      const float4 wg1 = *reinterpret_cast<const float4*>(gw + kL + k_);    \
      const float4 wg2 = *reinterpret_cast<const float4*>(gw + 2*kL + k_);  \
      const float4 wn0 = *reinterpret_cast<const float4*>(nw + k_);         \
      const float4 wn1 = *reinterpret_cast<const float4*>(nw + kL + k_);    \
      const float4 wn2 = *reinterpret_cast<const float4*>(nw + 2*kL + k_);  \
      const float4 xq = BUF[j_];                                            \
      accg[0] = fmaf(xq.x, wg0.x, accg[0]);                                 \
      accg[1] = fmaf(xq.x, wg1.x, accg[1]);                                 \
      accg[2] = fmaf(xq.x, wg2.x, accg[2]);                                 \
      accn[0] = fmaf(xq.x, wn0.x, accn[0]);                                 \
      accn[1] = fmaf(xq.x, wn1.x, accn[1]);                                 \
      accn[2] = fmaf(xq.x, wn2.x, accn[2]);                                 \
      accg[0] = fmaf(xq.y, wg0.y, accg[0]);                                 \
      accg[1] = fmaf(xq.y, wg1.y, accg[1]);                                 \
      accg[2] = fmaf(xq.y, wg2.y, accg[2]);                                 \
      accn[0] = fmaf(xq.y, wn0.y, accn[0]);                                 \
      accn[1] = fmaf(xq.y, wn1.y, accn[1]);                                 \
      accn[2] = fmaf(xq.y, wn2.y, accn[2]);                                 \
      accg[0] = fmaf(xq.z, wg0.z, accg[0]);                                 \
      accg[1] = fmaf(xq.z, wg1.z, accg[1]);                                 \
      accg[2] = fmaf(xq.z, wg2.z, accg[2]);                                 \
      accn[0] = fmaf(xq.z, wn0.z, accn[0]);                                 \
      accn[1] = fmaf(xq.z, wn1.z, accn[1]);                                 \
      accn[2] = fmaf(xq.z, wn2.z, accn[2]);                                 \
      accg[0] = fmaf(xq.w, wg0.w, accg[0]);                                 \
      accg[1] = fmaf(xq.w, wg1.w, accg[1]);                                 \
      accg[2] = fmaf(xq.w, wg2.w, accg[2]);                                 \
      accn[0] = fmaf(xq.w, wn0.w, accn[0]);                                 \
      accn[1] = fmaf(xq.w, wn1.w, accn[1]);                                 \
      accn[2] = fmaf(xq.w, wn2.w, accn[2]);                                 \
    }                                                                       \
  }

// ---------------------------------------------------------------------------
// Kernel 1: gating. One thread per row; x staged via double-buffered linear
// 256x32 LDS tiles using global_load_lds (async, no VGPR round-trip); XOR
// swizzle applied on BOTH the global source column and the LDS read slot.
// Wave wv stages chunks [wv*8, wv*8+8) == its own 64 rows. FROZEN FMA order.
// ---------------------------------------------------------------------------
__global__ __launch_bounds__(256) void gating_kernel(
    const float* __restrict__ x, const float* __restrict__ gw,
    const float* __restrict__ nw, float* __restrict__ g_out,
    float* __restrict__ kept_out, float* __restrict__ ent_out) {
  __shared__ float s_x[2][256 * 32];   // 2 x 32 KB, linear
  const int t = threadIdx.x;
  const int ln = t & 63;               // lane
  const int wv = t >> 6;               // wave id (uniform per wave)
  const int r = blockIdx.x * 256 + t;  // this thread's row
  const float* xblk = x + (size_t)blockIdx.x * 256 * kL;
  const int rowin = ln >> 3;                   // lane's row within 8-row chunk
  const int srcc4 = ((ln & 7) ^ rowin) * 4;    // pre-swizzled source col (floats)

  // stage tile cols [K0,K0+32) into buffer BUF: 8 x 1KB global_load_lds/wave
#define STAGE_GL(K0, BUF)                                                   \
  _Pragma("unroll")                                                         \
  for (int i_ = 0; i_ < 8; ++i_) {                                          \
    const int c_ = wv * 8 + i_;                                             \
    GLOAD_LDS16(xblk + (size_t)(c_ * 8 + rowin) * kL + (K0) + srcc4,        \
                &s_x[BUF][c_ * 256]);                                       \
  }

  // prologue: stage tile 0
  STAGE_GL(0, 0)
  __syncthreads();   // drains vmcnt(0): tile 0 resident

  float accg[3] = {0.f, 0.f, 0.f};
  float accn[3] = {0.f, 0.f, 0.f};
  const int sw = t & 7;                // read-side swizzle (row & 7)
  for (int tile = 0; tile < 16; ++tile) {
    const int k0 = tile * 32;
    if (tile < 15) { STAGE_GL(k0 + 32, (tile + 1) & 1) }  // async next tile
    {
#pragma clang fp contract(off)
      const float* xrow = &s_x[tile & 1][t * 32];
      float4 bufL[4];
      bufL[0] = *reinterpret_cast<const float4*>(xrow + ((0 ^ sw) << 2));
      bufL[1] = *reinterpret_cast<const float4*>(xrow + ((1 ^ sw) << 2));
      bufL[2] = *reinterpret_cast<const float4*>(xrow + ((2 ^ sw) << 2));
      bufL[3] = *reinterpret_cast<const float4*>(xrow + ((3 ^ sw) << 2));
      COMP16(bufL, k0)
      bufL[0] = *reinterpret_cast<const float4*>(xrow + ((4 ^ sw) << 2));
      bufL[1] = *reinterpret_cast<const float4*>(xrow + ((5 ^ sw) << 2));
      bufL[2] = *reinterpret_cast<const float4*>(xrow + ((6 ^ sw) << 2));
      bufL[3] = *reinterpret_cast<const float4*>(xrow + ((7 ^ sw) << 2));
      COMP16(bufL, k0 + 16)
    }
    __syncthreads();   // drains vmcnt(0): next tile resident; reads done
  }

  {
#pragma clang fp contract(off)
    float noisy[3];
    const uint32_t nbase = (uint32_t)r * 3u;
#pragma unroll
    for (int e = 0; e < 3; ++e) {
      const float cl = accg[e];
      const float sp = softplus_f32(accn[e]) + 0.01f;  // NOISE_EPS
      const float nz = bits_to_normal(jax_random_bits(nbase + (uint32_t)e));
      const float prod = nz * sp;        // separate rounding: mul then add
      noisy[e] = cl + prod;
    }
    // softmax over 3 experts (f32, max-subtracted)
    const float m = fmaxf(noisy[0], fmaxf(noisy[1], noisy[2]));
    float uu[3];
    uu[0] = expf(noisy[0] - m);
    uu[1] = expf(noisy[1] - m);
    uu[2] = expf(noisy[2] - m);
    const float ssum = (uu[0] + uu[1]) + uu[2];
    float p[3];
    p[0] = uu[0] / ssum;
    p[1] = uu[1] / ssum;
    p[2] = uu[2] / ssum;

    // stable descending argsort of 3
    int o0 = 0;
    if (p[1] > p[o0]) o0 = 1;
    if (p[2] > p[o0]) o0 = 2;
    const int i = (o0 == 0) ? 1 : 0;
    const int j = (o0 == 2) ? 1 : 2;
    const int o1 = (p[j] > p[i]) ? j : i;

    const float s0 = p[o0];
    const float s1 = p[o1];
    const bool keep2 = !(s0 > 0.5f);  // keep top-1 iff s0 > 0.5

    float g[3] = {0.f, 0.f, 0.f};
    g[o0] = 1.f;
    if (keep2) g[o1] = 1.f;

    float ent = 0.f;
    ent += p[0] * logf(p[0] + 1e-10f);
    ent += p[1] * logf(p[1] + 1e-10f);
    ent += p[2] * logf(p[2] + 1e-10f);

    const int bh = r >> 9;
    const int l = r & (kL - 1);
    g_out[r * 3 + 0] = g[0];
    g_out[r * 3 + 1] = g[1];
    g_out[r * 3 + 2] = g[2];
    // kept sorted probs, layout [jpos][l][bh] for coalesced reduction reads
    kept_out[(0 * kL + l) * kBH + bh] = s0;
    kept_out[(1 * kL + l) * kBH + bh] = keep2 ? s1 : 0.f;
    kept_out[(2 * kL + l) * kBH + bh] = 0.f;
    ent_out[r] = -ent;
  }
}

// ---------------------------------------------------------------------------
// Kernel 2a: parallel deterministic partials (r6-proven form).
// ---------------------------------------------------------------------------
__global__ __launch_bounds__(256) void loss_partial_kernel(
    const float* __restrict__ kept, const float* __restrict__ ent,
    double* __restrict__ imp_ws, double* __restrict__ ent_ws) {
  __shared__ double red[256];
  const int t = threadIdx.x;
  const int ln = t & 63;
  const int wg = blockIdx.x * 4 + (t >> 6);   // global wave id, 0..511

  // importance entries
#pragma unroll
  for (int rep = 0; rep < 3; ++rep) {
    const int q = wg + rep * 512;
    const float4 v = reinterpret_cast<const float4*>(kept + (size_t)q * kBH)[ln];
    double s = ((double)v.x + (double)v.y) + ((double)v.z + (double)v.w);
#pragma unroll
    for (int off = 32; off > 0; off >>= 1) s += __shfl_xor(s, off, 64);
    if (ln == 0) imp_ws[q] = s;
  }

  // entropy partial: fixed slice of 1024 rows
  double a = 0.0;
#pragma unroll
  for (int it = 0; it < 4; ++it) {
    a += (double)ent[blockIdx.x * 1024 + it * 256 + t];
  }
  red[t] = a;
  __syncthreads();
  for (int off = 128; off > 0; off >>= 1) {
    if (t < off) red[t] += red[t + off];
    __syncthreads();
  }
  if (t == 0) ent_ws[blockIdx.x] = red[0];
}

// ---------------------------------------------------------------------------
// Kernel 3 (fused, r16 form): block 0 computes final loss; all blocks write
// out with NON-TEMPORAL float4 stores. 16384 x 256; 8 rows/block.
// ---------------------------------------------------------------------------
__global__ __launch_bounds__(256) void out_kernel(
    const float* __restrict__ g, const double* __restrict__ imp_ws,
    const double* __restrict__ ent_ws, float* __restrict__ out,
    float* __restrict__ loss_out) {
  const int td = threadIdx.x;

  if (blockIdx.x == 0) {
    // final loss combine (identical math/order to r14 loss_final_kernel)
    __shared__ double red[256];
    __shared__ double s_mean;
    double a = 0.0;
    for (int i = td; i < kL * kE; i += 256) a += imp_ws[i];
    red[td] = a;
    __syncthreads();
    for (int off = 128; off > 0; off >>= 1) {
      if (td < off) red[td] += red[td + off];
      __syncthreads();
    }
    if (td == 0) s_mean = red[0] / (double)(kL * kE);
    __syncthreads();
    const double mean = s_mean;

    double sq = 0.0;
    for (int i = td; i < kL * kE; i += 256) {
      const double d = imp_ws[i] - mean;
      sq += d * d;
    }
    red[td] = sq;
    __syncthreads();
    for (int off = 128; off > 0; off >>= 1) {
      if (td < off) red[td] += red[td + off];
      __syncthreads();
    }
    const double var_sum = red[0];
    __syncthreads();

    double e = 0.0;
    for (int i = td; i < 128; i += 256) e += ent_ws[i];
    red[td] = e;
    __syncthreads();
    for (int off = 128; off > 0; off >>= 1) {
      if (td < off) red[td] += red[td + off];
      __syncthreads();
    }
    if (td == 0) {
      const double var = var_sum / (double)(kL * kE - 1);
      const double loss_imp = var / (mean * mean + 1e-10);
      const double loss_dyn = red[0] / 768.0;
      loss_out[0] = (float)(loss_imp + 0.1 * loss_dyn);
    }
  }

  const int r = blockIdx.x * 8 + (td >> 5);    // 8 rows, 32 threads each
  const int l = r & (kL - 1);
  const float g0 = g[r * 3 + 0];
  const float g1 = g[r * 3 + 1];
  const float g2 = g[r * 3 + 2];
  const int lblk = l >> 6;
  const int loff = l & 63;
  float* orow = out + (size_t)r * kL;
  const int c0 = (td & 31) * 4;
#pragma unroll
  for (int j = 0; j < 4; ++j) {
    const int d0 = c0 + j * 128;
    v4f vals;
#pragma unroll
    for (int k = 0; k < 4; ++k) {
      const int d = d0 + k;
      float v;
      if (((d & 63) == loff) && (d != l)) v = g0;     // S
      else if ((d >> 6) == lblk) v = g1;               // T (includes diagonal)
      else v = g2;                                     // ST
      if (d == l) v += 1.0f;                           // + eye
      vals[k] = v;
    }
    __builtin_nontemporal_store(vals, reinterpret_cast<v4f*>(orow + d0));
  }
}

}  // namespace

extern "C" void kernel_launch(void* const* d_in, const int* in_sizes, int n_in,
                              void* d_out, int out_size, void* d_ws, size_t ws_size,
                              hipStream_t stream) {
  (void)in_sizes; (void)n_in; (void)out_size; (void)ws_size;
  const float* x = (const float*)d_in[0];       // [B,H,L,L] = [32,8,512,512]
  const float* gw = (const float*)d_in[1];      // [3,512]
  const float* nw = (const float*)d_in[2];      // [3,512]
  float* out = (float*)d_out;                   // 64M out + 1 loss

  float* ws = (float*)d_ws;
  float* ws_g = ws;                               // kRows*3 floats
  float* ws_kept = ws + (size_t)kRows * 3;        // kRows*3 floats
  float* ws_ent = ws + (size_t)kRows * 6;         // kRows floats
  double* ws_imp = (double*)(ws + (size_t)kRows * 7);   // 1536 doubles (8B-aligned)
  double* ws_entp = ws_imp + kL * kE;                   // 128 doubles

  gating_kernel<<<kRows / 256, 256, 0, stream>>>(x, gw, nw, ws_g, ws_kept, ws_ent);
  loss_partial_kernel<<<128, 256, 0, stream>>>(ws_kept, ws_ent, ws_imp, ws_entp);
  out_kernel<<<kRows / 8, 256, 0, stream>>>(ws_g, ws_imp, ws_entp, out,
                                            out + (size_t)kBH * kL * kL);
}

// Round 23
// 117.182 us; speedup vs baseline: 1.1325x; 1.1325x over previous
//
#include <hip/hip_runtime.h>
#include <cstdint>
#include <cstddef>

// ---------------------------------------------------------------------------
// mask_moe: bit-exact vs harness reference (verified r4-r22, absmax 0.0).
// FROZEN arithmetic: partitionable threefry bits, f32 sequential-k FMA dots,
// f32 elementwise chain (softplus/normal/softmax), decision logic.
// Round 23: revert gating to r17 exact (r22 global_load_lds regressed: 1M
// bank conflicts). Hide the 8 us loss_partial dispatch: its body moves into
// out_kernel blocks 0..127 (runs under the 256 MB write stream); final
// combine becomes a ~2 us single-block kernel. Loss math/order identical.
// ---------------------------------------------------------------------------

namespace {

constexpr int kBH = 256;                  // B*H
constexpr int kL = 512;                   // L
constexpr int kE = 3;                     // experts
constexpr int kRows = kBH * kL;           // 131072 gating rows
constexpr int kPad = 36;                  // LDS row stride (floats): 144 B,
                                          // 16B-aligned, 2-way banks (free)

typedef float v4f __attribute__((ext_vector_type(4)));

__device__ __forceinline__ uint32_t rotl32(uint32_t v, int n) {
  return (v << n) | (v >> (32 - n));
}

// Threefry-2x32, 20 rounds, key = (0, 42)  [jax.random.key(42)]
__device__ __forceinline__ void threefry2x32_k42(uint32_t& x0, uint32_t& x1) {
  const uint32_t ks0 = 0u;
  const uint32_t ks1 = 42u;
  const uint32_t ks2 = 0u ^ 42u ^ 0x1BD11BDAu;
  x0 += ks0; x1 += ks1;
#define TF_ROUND(r) { x0 += x1; x1 = rotl32(x1, (r)); x1 ^= x0; }
  TF_ROUND(13) TF_ROUND(15) TF_ROUND(26) TF_ROUND(6)
  x0 += ks1; x1 += ks2 + 1u;
  TF_ROUND(17) TF_ROUND(29) TF_ROUND(16) TF_ROUND(24)
  x0 += ks2; x1 += ks0 + 2u;
  TF_ROUND(13) TF_ROUND(15) TF_ROUND(26) TF_ROUND(6)
  x0 += ks0; x1 += ks1 + 3u;
  TF_ROUND(17) TF_ROUND(29) TF_ROUND(16) TF_ROUND(24)
  x0 += ks1; x1 += ks2 + 4u;
  TF_ROUND(13) TF_ROUND(15) TF_ROUND(26) TF_ROUND(6)
  x0 += ks2; x1 += ks0 + 5u;
#undef TF_ROUND
}

// partitionable path: bits = x0 ^ x1 of threefry(key, (0, i))
__device__ __forceinline__ uint32_t jax_random_bits(uint32_t flat_idx) {
  uint32_t x0 = 0u;
  uint32_t x1 = flat_idx;
  threefry2x32_k42(x0, x1);
  return x0 ^ x1;
}

// jax.random.normal f32: uniform(-0.99999994, 1.0) then sqrt(2)*erfinv (XLA Giles poly)
__device__ float bits_to_normal(uint32_t bits) {
#pragma clang fp contract(off)
  const uint32_t fb = (bits >> 9) | 0x3F800000u;
  const float f = __uint_as_float(fb) - 1.0f;   // [0, 1)
  const float lo = -0.99999994f;                 // nextafterf(-1, 0)
  float u = f * 2.0f + lo;                       // (maxval-minval) == 2.0f exactly
  u = fmaxf(lo, u);
  float w = -log1pf(-(u * u));
  float p;
  if (w < 5.0f) {
    w = w - 2.5f;
    p = 2.81022636e-08f;
    p = 3.43273939e-07f + p * w;
    p = -3.5233877e-06f + p * w;
    p = -4.39150654e-06f + p * w;
    p = 0.00021858087f + p * w;
    p = -0.00125372503f + p * w;
    p = -0.00417768164f + p * w;
    p = 0.246640727f + p * w;
    p = 1.50140941f + p * w;
  } else {
    w = sqrtf(w) - 3.0f;
    p = -0.000200214257f;
    p = 0.000100950558f + p * w;
    p = 0.00134934322f + p * w;
    p = -0.00367342844f + p * w;
    p = 0.00573950773f + p * w;
    p = -0.0076224613f + p * w;
    p = 0.00943887047f + p * w;
    p = 1.00167406f + p * w;
    p = 2.83297682f + p * w;
  }
  const float einv = p * u;
  return 1.41421354f * einv;  // f32(sqrt(2)) * erfinv(u)
}

// jax.nn.softplus(x) = logaddexp(x, 0) = max(x,0) + log1p(exp(-|x|))
__device__ __forceinline__ float softplus_f32(float v) {
#pragma clang fp contract(off)
  const float amax = fmaxf(v, 0.0f);
  return amax + log1pf(expf(-fabsf(v)));
}

// 16 k-steps of the FROZEN ascending-k FMA sequence; weights via uniform
// global loads (gw/nw are const __restrict__).
#define COMP16(BUF, KB)                                                     \
  {                                                                         \
    _Pragma("unroll")                                                       \
    for (int j_ = 0; j_ < 4; ++j_) {                                        \
      const int k_ = (KB) + j_ * 4;                                         \
      const float4 wg0 = *reinterpret_cast<const float4*>(gw + k_);         \
      const float4 wg1 = *reinterpret_cast<const float4*>(gw + kL + k_);    \
      const float4 wg2 = *reinterpret_cast<const float4*>(gw + 2*kL + k_);  \
      const float4 wn0 = *reinterpret_cast<const float4*>(nw + k_);         \
      const float4 wn1 = *reinterpret_cast<const float4*>(nw + kL + k_);    \
      const float4 wn2 = *reinterpret_cast<const float4*>(nw + 2*kL + k_);  \
      const float4 xq = BUF[j_];                                            \
      accg[0] = fmaf(xq.x, wg0.x, accg[0]);                                 \
      accg[1] = fmaf(xq.x, wg1.x, accg[1]);                                 \
      accg[2] = fmaf(xq.x, wg2.x, accg[2]);                                 \
      accn[0] = fmaf(xq.x, wn0.x, accn[0]);                                 \
      accn[1] = fmaf(xq.x, wn1.x, accn[1]);                                 \
      accn[2] = fmaf(xq.x, wn2.x, accn[2]);                                 \
      accg[0] = fmaf(xq.y, wg0.y, accg[0]);                                 \
      accg[1] = fmaf(xq.y, wg1.y, accg[1]);                                 \
      accg[2] = fmaf(xq.y, wg2.y, accg[2]);                                 \
      accn[0] = fmaf(xq.y, wn0.y, accn[0]);                                 \
      accn[1] = fmaf(xq.y, wn1.y, accn[1]);                                 \
      accn[2] = fmaf(xq.y, wn2.y, accn[2]);                                 \
      accg[0] = fmaf(xq.z, wg0.z, accg[0]);                                 \
      accg[1] = fmaf(xq.z, wg1.z, accg[1]);                                 \
      accg[2] = fmaf(xq.z, wg2.z, accg[2]);                                 \
      accn[0] = fmaf(xq.z, wn0.z, accn[0]);                                 \
      accn[1] = fmaf(xq.z, wn1.z, accn[1]);                                 \
      accn[2] = fmaf(xq.z, wn2.z, accn[2]);                                 \
      accg[0] = fmaf(xq.w, wg0.w, accg[0]);                                 \
      accg[1] = fmaf(xq.w, wg1.w, accg[1]);                                 \
      accg[2] = fmaf(xq.w, wg2.w, accg[2]);                                 \
      accn[0] = fmaf(xq.w, wn0.w, accn[0]);                                 \
      accn[1] = fmaf(xq.w, wn1.w, accn[1]);                                 \
      accn[2] = fmaf(xq.w, wn2.w, accn[2]);                                 \
    }                                                                       \
  }

// cooperative tile load (r17 form): thread t grabs 8 float4s of tile cols
// [K0,K0+32); per instr: 8 x 128B contiguous segments (coalesced).
#define STAGE_LOAD(ST, K0)                                                  \
  _Pragma("unroll")                                                         \
  for (int i_ = 0; i_ < 8; ++i_) {                                          \
    const int fi_ = i_ * 256 + t;                                           \
    const int row_ = fi_ >> 3;                                              \
    const int c4_ = fi_ & 7;                                                \
    ST[i_] = *reinterpret_cast<const float4*>(                              \
        xblk + (size_t)row_ * kL + (K0) + c4_ * 4);                         \
  }

#define STAGE_WRITE(ST, BUF)                                                \
  _Pragma("unroll")                                                         \
  for (int i_ = 0; i_ < 8; ++i_) {                                          \
    const int fi_ = i_ * 256 + t;                                           \
    const int row_ = fi_ >> 3;                                              \
    const int c4_ = fi_ & 7;                                                \
    *reinterpret_cast<float4*>(&s_x[BUF][row_ * kPad + c4_ * 4]) = ST[i_];  \
  }

// ---------------------------------------------------------------------------
// Kernel 1: gating (r17 EXACT). One thread per row; x staged via
// double-buffered 256x32 LDS tiles (coalesced loads, pad-36 aligned b128
// reads); weights via uniform cached global loads. FROZEN FMA order.
// ---------------------------------------------------------------------------
__global__ __launch_bounds__(256) void gating_kernel(
    const float* __restrict__ x, const float* __restrict__ gw,
    const float* __restrict__ nw, float* __restrict__ g_out,
    float* __restrict__ kept_out, float* __restrict__ ent_out) {
  __shared__ float s_x[2][256 * kPad];   // 2 x 36,864 B
  const int t = threadIdx.x;
  const int r = blockIdx.x * 256 + t;    // this thread's row
  const float* xblk = x + (size_t)blockIdx.x * 256 * kL;

  // prologue: stage tile 0
  {
    float4 st[8];
    STAGE_LOAD(st, 0)
    STAGE_WRITE(st, 0)
  }
  __syncthreads();

  float accg[3] = {0.f, 0.f, 0.f};
  float accn[3] = {0.f, 0.f, 0.f};
  for (int tile = 0; tile < 16; ++tile) {
    const int k0 = tile * 32;
    float4 st[8];
    if (tile < 15) { STAGE_LOAD(st, k0 + 32) }   // issue next tile's loads
    {
#pragma clang fp contract(off)
      const float* xrow = &s_x[tile & 1][t * kPad];
      float4 bufL[4];
      bufL[0] = *reinterpret_cast<const float4*>(xrow);
      bufL[1] = *reinterpret_cast<const float4*>(xrow + 4);
      bufL[2] = *reinterpret_cast<const float4*>(xrow + 8);
      bufL[3] = *reinterpret_cast<const float4*>(xrow + 12);
      COMP16(bufL, k0)
      bufL[0] = *reinterpret_cast<const float4*>(xrow + 16);
      bufL[1] = *reinterpret_cast<const float4*>(xrow + 20);
      bufL[2] = *reinterpret_cast<const float4*>(xrow + 24);
      bufL[3] = *reinterpret_cast<const float4*>(xrow + 28);
      COMP16(bufL, k0 + 16)
    }
    if (tile < 15) { STAGE_WRITE(st, (tile + 1) & 1) }
    __syncthreads();
  }

  {
#pragma clang fp contract(off)
    float noisy[3];
    const uint32_t nbase = (uint32_t)r * 3u;
#pragma unroll
    for (int e = 0; e < 3; ++e) {
      const float cl = accg[e];
      const float sp = softplus_f32(accn[e]) + 0.01f;  // NOISE_EPS
      const float nz = bits_to_normal(jax_random_bits(nbase + (uint32_t)e));
      const float prod = nz * sp;        // separate rounding: mul then add
      noisy[e] = cl + prod;
    }
    // softmax over 3 experts (f32, max-subtracted)
    const float m = fmaxf(noisy[0], fmaxf(noisy[1], noisy[2]));
    float uu[3];
    uu[0] = expf(noisy[0] - m);
    uu[1] = expf(noisy[1] - m);
    uu[2] = expf(noisy[2] - m);
    const float ssum = (uu[0] + uu[1]) + uu[2];
    float p[3];
    p[0] = uu[0] / ssum;
    p[1] = uu[1] / ssum;
    p[2] = uu[2] / ssum;

    // stable descending argsort of 3
    int o0 = 0;
    if (p[1] > p[o0]) o0 = 1;
    if (p[2] > p[o0]) o0 = 2;
    const int i = (o0 == 0) ? 1 : 0;
    const int j = (o0 == 2) ? 1 : 2;
    const int o1 = (p[j] > p[i]) ? j : i;

    const float s0 = p[o0];
    const float s1 = p[o1];
    const bool keep2 = !(s0 > 0.5f);  // keep top-1 iff s0 > 0.5

    float g[3] = {0.f, 0.f, 0.f};
    g[o0] = 1.f;
    if (keep2) g[o1] = 1.f;

    float ent = 0.f;
    ent += p[0] * logf(p[0] + 1e-10f);
    ent += p[1] * logf(p[1] + 1e-10f);
    ent += p[2] * logf(p[2] + 1e-10f);

    const int bh = r >> 9;
    const int l = r & (kL - 1);
    g_out[r * 3 + 0] = g[0];
    g_out[r * 3 + 1] = g[1];
    g_out[r * 3 + 2] = g[2];
    // kept sorted probs, layout [jpos][l][bh] for coalesced reduction reads
    kept_out[(0 * kL + l) * kBH + bh] = s0;
    kept_out[(1 * kL + l) * kBH + bh] = keep2 ? s1 : 0.f;
    kept_out[(2 * kL + l) * kBH + bh] = 0.f;
    ent_out[r] = -ent;
  }
}

// ---------------------------------------------------------------------------
// Kernel 2 (out + hidden loss partials): all 16384 blocks write 8 rows with
// NON-TEMPORAL float4 stores; blocks 0..127 additionally compute the loss
// partials (importance: 4 waves x 3 entries, coalesced 1KB float4 + f64
// butterfly; entropy: 1024-row slice, f64 LDS tree) -- identical math/order
// to the r6 loss_partial_kernel, hidden under the 256 MB write stream.
// ---------------------------------------------------------------------------
__global__ __launch_bounds__(256) void out_kernel(
    const float* __restrict__ g, const float* __restrict__ kept,
    const float* __restrict__ ent, float* __restrict__ out,
    double* __restrict__ imp_ws, double* __restrict__ ent_ws) {
  const int td = threadIdx.x;

  if (blockIdx.x < 128) {
    __shared__ double red[256];
    const int ln = td & 63;
    const int wg = blockIdx.x * 4 + (td >> 6);   // global wave id, 0..511

    // importance entries
#pragma unroll
    for (int rep = 0; rep < 3; ++rep) {
      const int q = wg + rep * 512;
      const float4 v = reinterpret_cast<const float4*>(kept + (size_t)q * kBH)[ln];
      double s = ((double)v.x + (double)v.y) + ((double)v.z + (double)v.w);
#pragma unroll
      for (int off = 32; off > 0; off >>= 1) s += __shfl_xor(s, off, 64);
      if (ln == 0) imp_ws[q] = s;
    }

    // entropy partial: fixed slice of 1024 rows
    double a = 0.0;
#pragma unroll
    for (int it = 0; it < 4; ++it) {
      a += (double)ent[blockIdx.x * 1024 + it * 256 + td];
    }
    red[td] = a;
    __syncthreads();
    for (int off = 128; off > 0; off >>= 1) {
      if (td < off) red[td] += red[td + off];
      __syncthreads();
    }
    if (td == 0) ent_ws[blockIdx.x] = red[0];
  }

  const int r = blockIdx.x * 8 + (td >> 5);    // 8 rows, 32 threads each
  const int l = r & (kL - 1);
  const float g0 = g[r * 3 + 0];
  const float g1 = g[r * 3 + 1];
  const float g2 = g[r * 3 + 2];
  const int lblk = l >> 6;
  const int loff = l & 63;
  float* orow = out + (size_t)r * kL;
  const int c0 = (td & 31) * 4;
#pragma unroll
  for (int j = 0; j < 4; ++j) {
    const int d0 = c0 + j * 128;
    v4f vals;
#pragma unroll
    for (int k = 0; k < 4; ++k) {
      const int d = d0 + k;
      float v;
      if (((d & 63) == loff) && (d != l)) v = g0;     // S
      else if ((d >> 6) == lblk) v = g1;               // T (includes diagonal)
      else v = g2;                                     // ST
      if (d == l) v += 1.0f;                           // + eye
      vals[k] = v;
    }
    __builtin_nontemporal_store(vals, reinterpret_cast<v4f*>(orow + d0));
  }
}

// ---------------------------------------------------------------------------
// Kernel 3: final loss combine (1 block, ~2 us; r6-proven form).
// loss = var(importance, ddof=1)/(mean^2 + 1e-10) + 0.1 * ent_total/768
// ---------------------------------------------------------------------------
__global__ __launch_bounds__(256) void loss_final_kernel(
    const double* __restrict__ imp_ws, const double* __restrict__ ent_ws,
    float* __restrict__ loss_out) {
  __shared__ double red[256];
  __shared__ double s_mean;
  const int t = threadIdx.x;

  // mean of importance
  double a = 0.0;
  for (int i = t; i < kL * kE; i += 256) a += imp_ws[i];
  red[t] = a;
  __syncthreads();
  for (int off = 128; off > 0; off >>= 1) {
    if (t < off) red[t] += red[t + off];
    __syncthreads();
  }
  if (t == 0) s_mean = red[0] / (double)(kL * kE);
  __syncthreads();
  const double mean = s_mean;

  // variance (two-pass, ddof=1)
  double sq = 0.0;
  for (int i = t; i < kL * kE; i += 256) {
    const double d = imp_ws[i] - mean;
    sq += d * d;
  }
  red[t] = sq;
  __syncthreads();
  for (int off = 128; off > 0; off >>= 1) {
    if (t < off) red[t] += red[t + off];
    __syncthreads();
  }
  const double var_sum = red[0];
  __syncthreads();

  // entropy total
  double e = 0.0;
  for (int i = t; i < 128; i += 256) e += ent_ws[i];
  red[t] = e;
  __syncthreads();
  for (int off = 128; off > 0; off >>= 1) {
    if (t < off) red[t] += red[t + off];
    __syncthreads();
  }
  if (t == 0) {
    const double var = var_sum / (double)(kL * kE - 1);
    const double loss_imp = var / (mean * mean + 1e-10);
    const double loss_dyn = red[0] / 768.0;  // sum(axis=1).mean() over [BH,E]
    loss_out[0] = (float)(loss_imp + 0.1 * loss_dyn);
  }
}

}  // namespace

extern "C" void kernel_launch(void* const* d_in, const int* in_sizes, int n_in,
                              void* d_out, int out_size, void* d_ws, size_t ws_size,
                              hipStream_t stream) {
  (void)in_sizes; (void)n_in; (void)out_size; (void)ws_size;
  const float* x = (const float*)d_in[0];       // [B,H,L,L] = [32,8,512,512]
  const float* gw = (const float*)d_in[1];      // [3,512]
  const float* nw = (const float*)d_in[2];      // [3,512]
  float* out = (float*)d_out;                   // 64M out + 1 loss

  float* ws = (float*)d_ws;
  float* ws_g = ws;                               // kRows*3 floats
  float* ws_kept = ws + (size_t)kRows * 3;        // kRows*3 floats
  float* ws_ent = ws + (size_t)kRows * 6;         // kRows floats
  double* ws_imp = (double*)(ws + (size_t)kRows * 7);   // 1536 doubles (8B-aligned)
  double* ws_entp = ws_imp + kL * kE;                   // 128 doubles

  gating_kernel<<<kRows / 256, 256, 0, stream>>>(x, gw, nw, ws_g, ws_kept, ws_ent);
  out_kernel<<<kRows / 8, 256, 0, stream>>>(ws_g, ws_kept, ws_ent, out,
                                            ws_imp, ws_entp);
  loss_final_kernel<<<1, 256, 0, stream>>>(ws_imp, ws_entp,
                                           out + (size_t)kBH * kL * kL);
}

// Round 24
// 114.843 us; speedup vs baseline: 1.1556x; 1.0204x over previous
//
#include <hip/hip_runtime.h>
#include <cstdint>
#include <cstddef>

// ---------------------------------------------------------------------------
// mask_moe FINAL: bit-exact vs harness reference (absmax 0.0, r4-r23).
// FROZEN arithmetic: partitionable threefry bits, f32 sequential-k FMA dots,
// f32 elementwise chain (softplus/normal/softmax), decision logic.
// Round 24: restore r17-exact pipeline -- the measured optimum (114.8 us).
//   K1 gating: 1 thread/row, double-buffered 256x32 LDS x-tiles (pad-36,
//      coalesced loads, aligned b128 reads), uniform global weight loads.
//   K2 loss partials: 128 blocks, coalesced f64 reductions (hidden cost).
//   K3 out: NT float4 stores (L2 bypass; +17 us win) + merged loss-final.
// Lever history: r16 NT stores ✓, r17 LDS tiles ✓; r15 chain-split ✗✗,
// r18 small tiles ✗, r19 NT loads –, r20 no barriers ✗, r21 atomics ✗,
// r22 global_load_lds ✗✗, r23 folded partials –. Structural floor reached.
// ---------------------------------------------------------------------------

namespace {

constexpr int kBH = 256;                  // B*H
constexpr int kL = 512;                   // L
constexpr int kE = 3;                     // experts
constexpr int kRows = kBH * kL;           // 131072 gating rows
constexpr int kPad = 36;                  // LDS row stride (floats): 144 B,
                                          // 16B-aligned, 2-way banks (free)

typedef float v4f __attribute__((ext_vector_type(4)));

__device__ __forceinline__ uint32_t rotl32(uint32_t v, int n) {
  return (v << n) | (v >> (32 - n));
}

// Threefry-2x32, 20 rounds, key = (0, 42)  [jax.random.key(42)]
__device__ __forceinline__ void threefry2x32_k42(uint32_t& x0, uint32_t& x1) {
  const uint32_t ks0 = 0u;
  const uint32_t ks1 = 42u;
  const uint32_t ks2 = 0u ^ 42u ^ 0x1BD11BDAu;
  x0 += ks0; x1 += ks1;
#define TF_ROUND(r) { x0 += x1; x1 = rotl32(x1, (r)); x1 ^= x0; }
  TF_ROUND(13) TF_ROUND(15) TF_ROUND(26) TF_ROUND(6)
  x0 += ks1; x1 += ks2 + 1u;
  TF_ROUND(17) TF_ROUND(29) TF_ROUND(16) TF_ROUND(24)
  x0 += ks2; x1 += ks0 + 2u;
  TF_ROUND(13) TF_ROUND(15) TF_ROUND(26) TF_ROUND(6)
  x0 += ks0; x1 += ks1 + 3u;
  TF_ROUND(17) TF_ROUND(29) TF_ROUND(16) TF_ROUND(24)
  x0 += ks1; x1 += ks2 + 4u;
  TF_ROUND(13) TF_ROUND(15) TF_ROUND(26) TF_ROUND(6)
  x0 += ks2; x1 += ks0 + 5u;
#undef TF_ROUND
}

// partitionable path: bits = x0 ^ x1 of threefry(key, (0, i))
__device__ __forceinline__ uint32_t jax_random_bits(uint32_t flat_idx) {
  uint32_t x0 = 0u;
  uint32_t x1 = flat_idx;
  threefry2x32_k42(x0, x1);
  return x0 ^ x1;
}

// jax.random.normal f32: uniform(-0.99999994, 1.0) then sqrt(2)*erfinv (XLA Giles poly)
__device__ float bits_to_normal(uint32_t bits) {
#pragma clang fp contract(off)
  const uint32_t fb = (bits >> 9) | 0x3F800000u;
  const float f = __uint_as_float(fb) - 1.0f;   // [0, 1)
  const float lo = -0.99999994f;                 // nextafterf(-1, 0)
  float u = f * 2.0f + lo;                       // (maxval-minval) == 2.0f exactly
  u = fmaxf(lo, u);
  float w = -log1pf(-(u * u));
  float p;
  if (w < 5.0f) {
    w = w - 2.5f;
    p = 2.81022636e-08f;
    p = 3.43273939e-07f + p * w;
    p = -3.5233877e-06f + p * w;
    p = -4.39150654e-06f + p * w;
    p = 0.00021858087f + p * w;
    p = -0.00125372503f + p * w;
    p = -0.00417768164f + p * w;
    p = 0.246640727f + p * w;
    p = 1.50140941f + p * w;
  } else {
    w = sqrtf(w) - 3.0f;
    p = -0.000200214257f;
    p = 0.000100950558f + p * w;
    p = 0.00134934322f + p * w;
    p = -0.00367342844f + p * w;
    p = 0.00573950773f + p * w;
    p = -0.0076224613f + p * w;
    p = 0.00943887047f + p * w;
    p = 1.00167406f + p * w;
    p = 2.83297682f + p * w;
  }
  const float einv = p * u;
  return 1.41421354f * einv;  // f32(sqrt(2)) * erfinv(u)
}

// jax.nn.softplus(x) = logaddexp(x, 0) = max(x,0) + log1p(exp(-|x|))
__device__ __forceinline__ float softplus_f32(float v) {
#pragma clang fp contract(off)
  const float amax = fmaxf(v, 0.0f);
  return amax + log1pf(expf(-fabsf(v)));
}

// 16 k-steps of the FROZEN ascending-k FMA sequence; weights via uniform
// global loads (gw/nw are const __restrict__).
#define COMP16(BUF, KB)                                                     \
  {                                                                         \
    _Pragma("unroll")                                                       \
    for (int j_ = 0; j_ < 4; ++j_) {                                        \
      const int k_ = (KB) + j_ * 4;                                         \
      const float4 wg0 = *reinterpret_cast<const float4*>(gw + k_);         \
      const float4 wg1 = *reinterpret_cast<const float4*>(gw + kL + k_);    \
      const float4 wg2 = *reinterpret_cast<const float4*>(gw + 2*kL + k_);  \
      const float4 wn0 = *reinterpret_cast<const float4*>(nw + k_);         \
      const float4 wn1 = *reinterpret_cast<const float4*>(nw + kL + k_);    \
      const float4 wn2 = *reinterpret_cast<const float4*>(nw + 2*kL + k_);  \
      const float4 xq = BUF[j_];                                            \
      accg[0] = fmaf(xq.x, wg0.x, accg[0]);                                 \
      accg[1] = fmaf(xq.x, wg1.x, accg[1]);                                 \
      accg[2] = fmaf(xq.x, wg2.x, accg[2]);                                 \
      accn[0] = fmaf(xq.x, wn0.x, accn[0]);                                 \
      accn[1] = fmaf(xq.x, wn1.x, accn[1]);                                 \
      accn[2] = fmaf(xq.x, wn2.x, accn[2]);                                 \
      accg[0] = fmaf(xq.y, wg0.y, accg[0]);                                 \
      accg[1] = fmaf(xq.y, wg1.y, accg[1]);                                 \
      accg[2] = fmaf(xq.y, wg2.y, accg[2]);                                 \
      accn[0] = fmaf(xq.y, wn0.y, accn[0]);                                 \
      accn[1] = fmaf(xq.y, wn1.y, accn[1]);                                 \
      accn[2] = fmaf(xq.y, wn2.y, accn[2]);                                 \
      accg[0] = fmaf(xq.z, wg0.z, accg[0]);                                 \
      accg[1] = fmaf(xq.z, wg1.z, accg[1]);                                 \
      accg[2] = fmaf(xq.z, wg2.z, accg[2]);                                 \
      accn[0] = fmaf(xq.z, wn0.z, accn[0]);                                 \
      accn[1] = fmaf(xq.z, wn1.z, accn[1]);                                 \
      accn[2] = fmaf(xq.z, wn2.z, accn[2]);                                 \
      accg[0] = fmaf(xq.w, wg0.w, accg[0]);                                 \
      accg[1] = fmaf(xq.w, wg1.w, accg[1]);                                 \
      accg[2] = fmaf(xq.w, wg2.w, accg[2]);                                 \
      accn[0] = fmaf(xq.w, wn0.w, accn[0]);                                 \
      accn[1] = fmaf(xq.w, wn1.w, accn[1]);                                 \
      accn[2] = fmaf(xq.w, wn2.w, accn[2]);                                 \
    }                                                                       \
  }

// cooperative tile load: thread t grabs 8 float4s of tile cols [K0,K0+32);
// per instr: 8 x 128B contiguous segments (coalesced).
#define STAGE_LOAD(ST, K0)                                                  \
  _Pragma("unroll")                                                         \
  for (int i_ = 0; i_ < 8; ++i_) {                                          \
    const int fi_ = i_ * 256 + t;                                           \
    const int row_ = fi_ >> 3;                                              \
    const int c4_ = fi_ & 7;                                                \
    ST[i_] = *reinterpret_cast<const float4*>(                              \
        xblk + (size_t)row_ * kL + (K0) + c4_ * 4);                         \
  }

#define STAGE_WRITE(ST, BUF)                                                \
  _Pragma("unroll")                                                         \
  for (int i_ = 0; i_ < 8; ++i_) {                                          \
    const int fi_ = i_ * 256 + t;                                           \
    const int row_ = fi_ >> 3;                                              \
    const int c4_ = fi_ & 7;                                                \
    *reinterpret_cast<float4*>(&s_x[BUF][row_ * kPad + c4_ * 4]) = ST[i_];  \
  }

// ---------------------------------------------------------------------------
// Kernel 1: gating (r17 exact). One thread per row; x staged via
// double-buffered 256x32 LDS tiles; weights via uniform cached global loads.
// FROZEN f32 sequential-k FMA order per expert.
// ---------------------------------------------------------------------------
__global__ __launch_bounds__(256) void gating_kernel(
    const float* __restrict__ x, const float* __restrict__ gw,
    const float* __restrict__ nw, float* __restrict__ g_out,
    float* __restrict__ kept_out, float* __restrict__ ent_out) {
  __shared__ float s_x[2][256 * kPad];   // 2 x 36,864 B
  const int t = threadIdx.x;
  const int r = blockIdx.x * 256 + t;    // this thread's row
  const float* xblk = x + (size_t)blockIdx.x * 256 * kL;

  // prologue: stage tile 0
  {
    float4 st[8];
    STAGE_LOAD(st, 0)
    STAGE_WRITE(st, 0)
  }
  __syncthreads();

  float accg[3] = {0.f, 0.f, 0.f};
  float accn[3] = {0.f, 0.f, 0.f};
  for (int tile = 0; tile < 16; ++tile) {
    const int k0 = tile * 32;
    float4 st[8];
    if (tile < 15) { STAGE_LOAD(st, k0 + 32) }   // issue next tile's loads
    {
#pragma clang fp contract(off)
      const float* xrow = &s_x[tile & 1][t * kPad];
      float4 bufL[4];
      bufL[0] = *reinterpret_cast<const float4*>(xrow);
      bufL[1] = *reinterpret_cast<const float4*>(xrow + 4);
      bufL[2] = *reinterpret_cast<const float4*>(xrow + 8);
      bufL[3] = *reinterpret_cast<const float4*>(xrow + 12);
      COMP16(bufL, k0)
      bufL[0] = *reinterpret_cast<const float4*>(xrow + 16);
      bufL[1] = *reinterpret_cast<const float4*>(xrow + 20);
      bufL[2] = *reinterpret_cast<const float4*>(xrow + 24);
      bufL[3] = *reinterpret_cast<const float4*>(xrow + 28);
      COMP16(bufL, k0 + 16)
    }
    if (tile < 15) { STAGE_WRITE(st, (tile + 1) & 1) }
    __syncthreads();
  }

  {
#pragma clang fp contract(off)
    float noisy[3];
    const uint32_t nbase = (uint32_t)r * 3u;
#pragma unroll
    for (int e = 0; e < 3; ++e) {
      const float cl = accg[e];
      const float sp = softplus_f32(accn[e]) + 0.01f;  // NOISE_EPS
      const float nz = bits_to_normal(jax_random_bits(nbase + (uint32_t)e));
      const float prod = nz * sp;        // separate rounding: mul then add
      noisy[e] = cl + prod;
    }
    // softmax over 3 experts (f32, max-subtracted)
    const float m = fmaxf(noisy[0], fmaxf(noisy[1], noisy[2]));
    float uu[3];
    uu[0] = expf(noisy[0] - m);
    uu[1] = expf(noisy[1] - m);
    uu[2] = expf(noisy[2] - m);
    const float ssum = (uu[0] + uu[1]) + uu[2];
    float p[3];
    p[0] = uu[0] / ssum;
    p[1] = uu[1] / ssum;
    p[2] = uu[2] / ssum;

    // stable descending argsort of 3
    int o0 = 0;
    if (p[1] > p[o0]) o0 = 1;
    if (p[2] > p[o0]) o0 = 2;
    const int i = (o0 == 0) ? 1 : 0;
    const int j = (o0 == 2) ? 1 : 2;
    const int o1 = (p[j] > p[i]) ? j : i;

    const float s0 = p[o0];
    const float s1 = p[o1];
    const bool keep2 = !(s0 > 0.5f);  // keep top-1 iff s0 > 0.5

    float g[3] = {0.f, 0.f, 0.f};
    g[o0] = 1.f;
    if (keep2) g[o1] = 1.f;

    float ent = 0.f;
    ent += p[0] * logf(p[0] + 1e-10f);
    ent += p[1] * logf(p[1] + 1e-10f);
    ent += p[2] * logf(p[2] + 1e-10f);

    const int bh = r >> 9;
    const int l = r & (kL - 1);
    g_out[r * 3 + 0] = g[0];
    g_out[r * 3 + 1] = g[1];
    g_out[r * 3 + 2] = g[2];
    // kept sorted probs, layout [jpos][l][bh] for coalesced reduction reads
    kept_out[(0 * kL + l) * kBH + bh] = s0;
    kept_out[(1 * kL + l) * kBH + bh] = keep2 ? s1 : 0.f;
    kept_out[(2 * kL + l) * kBH + bh] = 0.f;
    ent_out[r] = -ent;
  }
}

// ---------------------------------------------------------------------------
// Kernel 2a: parallel deterministic partials (r6-proven form).
// ---------------------------------------------------------------------------
__global__ __launch_bounds__(256) void loss_partial_kernel(
    const float* __restrict__ kept, const float* __restrict__ ent,
    double* __restrict__ imp_ws, double* __restrict__ ent_ws) {
  __shared__ double red[256];
  const int t = threadIdx.x;
  const int ln = t & 63;
  const int wg = blockIdx.x * 4 + (t >> 6);   // global wave id, 0..511

  // importance entries
#pragma unroll
  for (int rep = 0; rep < 3; ++rep) {
    const int q = wg + rep * 512;
    const float4 v = reinterpret_cast<const float4*>(kept + (size_t)q * kBH)[ln];
    double s = ((double)v.x + (double)v.y) + ((double)v.z + (double)v.w);
#pragma unroll
    for (int off = 32; off > 0; off >>= 1) s += __shfl_xor(s, off, 64);
    if (ln == 0) imp_ws[q] = s;
  }

  // entropy partial: fixed slice of 1024 rows
  double a = 0.0;
#pragma unroll
  for (int it = 0; it < 4; ++it) {
    a += (double)ent[blockIdx.x * 1024 + it * 256 + t];
  }
  red[t] = a;
  __syncthreads();
  for (int off = 128; off > 0; off >>= 1) {
    if (t < off) red[t] += red[t + off];
    __syncthreads();
  }
  if (t == 0) ent_ws[blockIdx.x] = red[0];
}

// ---------------------------------------------------------------------------
// Kernel 3 (fused, r16 form): block 0 computes final loss; all blocks write
// out with NON-TEMPORAL float4 stores. 16384 x 256; 8 rows/block.
// ---------------------------------------------------------------------------
__global__ __launch_bounds__(256) void out_kernel(
    const float* __restrict__ g, const double* __restrict__ imp_ws,
    const double* __restrict__ ent_ws, float* __restrict__ out,
    float* __restrict__ loss_out) {
  const int td = threadIdx.x;

  if (blockIdx.x == 0) {
    // final loss combine (identical math/order to r14 loss_final_kernel)
    __shared__ double red[256];
    __shared__ double s_mean;
    double a = 0.0;
    for (int i = td; i < kL * kE; i += 256) a += imp_ws[i];
    red[td] = a;
    __syncthreads();
    for (int off = 128; off > 0; off >>= 1) {
      if (td < off) red[td] += red[td + off];
      __syncthreads();
    }
    if (td == 0) s_mean = red[0] / (double)(kL * kE);
    __syncthreads();
    const double mean = s_mean;

    double sq = 0.0;
    for (int i = td; i < kL * kE; i += 256) {
      const double d = imp_ws[i] - mean;
      sq += d * d;
    }
    red[td] = sq;
    __syncthreads();
    for (int off = 128; off > 0; off >>= 1) {
      if (td < off) red[td] += red[td + off];
      __syncthreads();
    }
    const double var_sum = red[0];
    __syncthreads();

    double e = 0.0;
    for (int i = td; i < 128; i += 256) e += ent_ws[i];
    red[td] = e;
    __syncthreads();
    for (int off = 128; off > 0; off >>= 1) {
      if (td < off) red[td] += red[td + off];
      __syncthreads();
    }
    if (td == 0) {
      const double var = var_sum / (double)(kL * kE - 1);
      const double loss_imp = var / (mean * mean + 1e-10);
      const double loss_dyn = red[0] / 768.0;
      loss_out[0] = (float)(loss_imp + 0.1 * loss_dyn);
    }
  }

  const int r = blockIdx.x * 8 + (td >> 5);    // 8 rows, 32 threads each
  const int l = r & (kL - 1);
  const float g0 = g[r * 3 + 0];
  const float g1 = g[r * 3 + 1];
  const float g2 = g[r * 3 + 2];
  const int lblk = l >> 6;
  const int loff = l & 63;
  float* orow = out + (size_t)r * kL;
  const int c0 = (td & 31) * 4;
#pragma unroll
  for (int j = 0; j < 4; ++j) {
    const int d0 = c0 + j * 128;
    v4f vals;
#pragma unroll
    for (int k = 0; k < 4; ++k) {
      const int d = d0 + k;
      float v;
      if (((d & 63) == loff) && (d != l)) v = g0;     // S
      else if ((d >> 6) == lblk) v = g1;               // T (includes diagonal)
      else v = g2;                                     // ST
      if (d == l) v += 1.0f;                           // + eye
      vals[k] = v;
    }
    __builtin_nontemporal_store(vals, reinterpret_cast<v4f*>(orow + d0));
  }
}

}  // namespace

extern "C" void kernel_launch(void* const* d_in, const int* in_sizes, int n_in,
                              void* d_out, int out_size, void* d_ws, size_t ws_size,
                              hipStream_t stream) {
  (void)in_sizes; (void)n_in; (void)out_size; (void)ws_size;
  const float* x = (const float*)d_in[0];       // [B,H,L,L] = [32,8,512,512]
  const float* gw = (const float*)d_in[1];      // [3,512]
  const float* nw = (const float*)d_in[2];      // [3,512]
  float* out = (float*)d_out;                   // 64M out + 1 loss

  float* ws = (float*)d_ws;
  float* ws_g = ws;                               // kRows*3 floats
  float* ws_kept = ws + (size_t)kRows * 3;        // kRows*3 floats
  float* ws_ent = ws + (size_t)kRows * 6;         // kRows floats
  double* ws_imp = (double*)(ws + (size_t)kRows * 7);   // 1536 doubles (8B-aligned)
  double* ws_entp = ws_imp + kL * kE;                   // 128 doubles

  gating_kernel<<<kRows / 256, 256, 0, stream>>>(x, gw, nw, ws_g, ws_kept, ws_ent);
  loss_partial_kernel<<<128, 256, 0, stream>>>(ws_kept, ws_ent, ws_imp, ws_entp);
  out_kernel<<<kRows / 8, 256, 0, stream>>>(ws_g, ws_imp, ws_entp, out,
                                            out + (size_t)kBH * kL * kL);
}